// Round 1
// baseline (1264.104 us; speedup 1.0000x reference)
//
#include <hip/hip_runtime.h>

#define DEG 16
#define DD  128
#define KT  10      // template nodes
#define TT  10      // templates
#define MM  17      // m = DEG+1
#define NPB 4       // nodes per block
#define THREADS 640 // 10 waves: wave w <-> template w

#if __has_builtin(__builtin_amdgcn_exp2f)
#define FEXP2(x) __builtin_amdgcn_exp2f(x)
#else
#define FEXP2(x) exp2f(x)
#endif

#if __has_builtin(__builtin_amdgcn_rcpf)
#define FRCP(x) __builtin_amdgcn_rcpf(x)
#else
#define FRCP(x) (1.0f / (x))
#endif

// 2 * log2(e) = (1/EPS) * log2(e) with EPS = 0.5
#define TWO_LOG2E 2.8853900817779268f

__global__ __launch_bounds__(THREADS) void ltfgw_kernel(
    const float* __restrict__ x,      // [N,128]
    const int*   __restrict__ ei,     // edge_index[0], [N*DEG]
    const float* __restrict__ tmpl,   // [T,K,K]
    const float* __restrict__ tf,     // [T,K,128]
    float* __restrict__ out,          // [N,T]
    int N)
{
    constexpr int SLAB = MM * DD + 4;   // +4 floats: node slabs land on disjoint banks
    __shared__ float sFi[NPB * SLAB];
    __shared__ float sNrm[NPB][MM];

    const int tid = threadIdx.x;
    const int b0  = blockIdx.x * NPB;

    // ---- stage Fi: 68 rows of 128 floats, 32 threads (8 float4 lanes... 32 f4) per row
    {
        const int kq = tid & 31;                 // float4 index within row
        for (int r = tid >> 5; r < NPB * MM; r += (THREADS >> 5)) {
            int p = r / MM, j = r % MM;
            int node = b0 + p;
            if (node < N) {
                int src = (j == 0) ? node : ei[node * DEG + (j - 1)];
                float4 v = *(const float4*)(x + (size_t)src * DD + kq * 4);
                *(float4*)(&sFi[p * SLAB + j * DD + kq * 4]) = v;
            }
        }
    }
    __syncthreads();

    // ---- per-row squared norms (one thread per row; k rotated to spread banks)
    if (tid < NPB * MM) {
        int p = tid / MM, j = tid % MM;
        const float* row = &sFi[p * SLAB + j * DD];
        float acc = 0.f;
        for (int kidx = 0; kidx < 32; ++kidx) {
            int kq2 = (kidx + tid) & 31;
            float4 v = *(const float4*)(row + kq2 * 4);
            acc += v.x * v.x + v.y * v.y + v.z * v.z + v.w * v.w;
        }
        sNrm[p][j] = acc;
    }
    __syncthreads();

    const int w    = tid >> 6;         // template index
    const int lane = tid & 63;
    const int p    = lane >> 4;        // node sub-slot 0..3
    const int c    = lane & 15;        // template column (active if <10)
    const bool act = (c < KT);
    const int node = b0 + p;
    const int cc   = act ? c : 0;

    // ---- Ct row + ct2q = (Ct^2 @ q)[c]
    float CtRow[KT];
    float ct2q = 0.f;
#pragma unroll
    for (int jj = 0; jj < KT; ++jj) {
        CtRow[jj] = tmpl[(w * KT + cc) * KT + jj];
        ct2q += CtRow[jj] * CtRow[jj];
    }
    ct2q *= (1.f / KT);

    // ---- M[j][c] = (||Fi_j||^2 + ||Ft_c||^2 - 2*dot) / 128
    float dot[MM];
#pragma unroll
    for (int j = 0; j < MM; ++j) dot[j] = 0.f;
    float nft = 0.f;
    const float* ftrow = tf + (size_t)(w * KT + cc) * DD;
    for (int kk = 0; kk < DD; kk += 4) {
        float4 f4 = *(const float4*)(ftrow + kk);
        nft += f4.x * f4.x + f4.y * f4.y + f4.z * f4.z + f4.w * f4.w;
#pragma unroll
        for (int j = 0; j < MM; ++j) {
            float4 a4 = *(const float4*)(&sFi[p * SLAB + j * DD + kk]);
            dot[j] += a4.x * f4.x + a4.y * f4.y + a4.z * f4.z + a4.w * f4.w;
        }
    }
    float Mc[MM];
#pragma unroll
    for (int j = 0; j < MM; ++j)
        Mc[j] = act ? (sNrm[p][j] + nft - 2.f * dot[j]) * (1.f / DD) : 0.f;

    // ---- scaled-domain proximal Sinkhorn
    const float pw = 1.f / MM, qw = 1.f / KT;
    float eK[MM], u[MM];
    float v = 1.f;
#pragma unroll
    for (int j = 0; j < MM; ++j) { eK[j] = act ? (1.f / (MM * KT)) : 0.f; u[j] = 1.f; }

    const int gbase = lane & ~15;
    float obj = 0.f;

#pragma unroll 1
    for (int outer = 0; outer <= 5; ++outer) {
        // current plan Tp = eK * u * v  (outer 0: uniform 1/170)
        float Tp[MM];
        float colsum = 0.f;
#pragma unroll
        for (int j = 0; j < MM; ++j) { Tp[j] = eK[j] * u[j] * v; colsum += Tp[j]; }
        float t0 = Tp[0];
        float s  = colsum - t0;

        // (Ci@Tp@Ct^T): row0 -> Ct . s ; rows>=1 -> Ct . Tp[0,:]
        float Cs = 0.f, C0 = 0.f;
#pragma unroll
        for (int jj = 0; jj < KT; ++jj) {
            float sv = __shfl(s,  gbase + jj, 64);
            float tv = __shfl(t0, gbase + jj, 64);
            Cs += CtRow[jj] * sv;
            C0 += CtRow[jj] * tv;
        }

        if (outer == 5) {
#pragma unroll
            for (int j = 0; j < MM; ++j) {
                float gw = ((j == 0) ? (16.f / 17.f) : (1.f / 17.f)) + ct2q
                           - 2.f * ((j == 0) ? Cs : C0);
                obj += Tp[j] * (0.5f * Mc[j] + 0.5f * gw);
            }
            break;
        }

        // mirror step: eK = Tp * exp(-cost/EPS), cost = 0.5*M + gw_tens
#pragma unroll
        for (int j = 0; j < MM; ++j) {
            float gw = ((j == 0) ? (16.f / 17.f) : (1.f / 17.f)) + ct2q
                       - 2.f * ((j == 0) ? Cs : C0);
            float cost = 0.5f * Mc[j] + gw;
            eK[j] = act ? Tp[j] * FEXP2(-TWO_LOG2E * cost) : 0.f;
            u[j] = 1.f;
        }
        v = 1.f;

        // 10 Sinkhorn iterations: u = p./(K v); v = q./(K^T u)
#pragma unroll 1
        for (int it = 0; it < 10; ++it) {
            float colacc = 0.f;
#pragma unroll
            for (int j = 0; j < MM; ++j) {
                float t = eK[j] * v;
                t += __shfl_xor(t, 1);
                t += __shfl_xor(t, 2);
                t += __shfl_xor(t, 4);
                t += __shfl_xor(t, 8);
                u[j] = pw * FRCP(t);
                colacc += eK[j] * u[j];
            }
            v = act ? qw * FRCP(colacc) : 0.f;
        }
    }

    // sum over the 16-lane group (inactive lanes contribute exact 0)
    obj += __shfl_xor(obj, 1);
    obj += __shfl_xor(obj, 2);
    obj += __shfl_xor(obj, 4);
    obj += __shfl_xor(obj, 8);

    if (act && c == 0 && node < N) out[node * TT + w] = obj;
}

extern "C" void kernel_launch(void* const* d_in, const int* in_sizes, int n_in,
                              void* d_out, int out_size, void* d_ws, size_t ws_size,
                              hipStream_t stream) {
    const float* x    = (const float*)d_in[0];
    const int*   ei   = (const int*)d_in[1];
    const float* tmpl = (const float*)d_in[2];
    const float* tf   = (const float*)d_in[3];
    float* out = (float*)d_out;
    int N = in_sizes[0] / DD;
    int grid = (N + NPB - 1) / NPB;
    hipLaunchKernelGGL(ltfgw_kernel, dim3(grid), dim3(THREADS), 0, stream,
                       x, ei, tmpl, tf, out, N);
}

// Round 3
// 654.277 us; speedup vs baseline: 1.9321x; 1.9321x over previous
//
#include <hip/hip_runtime.h>

#define DEG 16
#define DD  128
#define KT  10      // template nodes
#define TT  10      // templates
#define MM  17      // m = DEG+1
#define NPB 4       // nodes per block
#define THREADS 640 // 10 waves: wave w <-> template w

#if __has_builtin(__builtin_amdgcn_exp2f)
#define FEXP2(x) __builtin_amdgcn_exp2f(x)
#else
#define FEXP2(x) exp2f(x)
#endif

#if __has_builtin(__builtin_amdgcn_rcpf)
#define FRCP(x) __builtin_amdgcn_rcpf(x)
#else
#define FRCP(x) (1.0f / (x))
#endif

// (1/EPS) * log2(e) with EPS = 0.5
#define TWO_LOG2E 2.8853900817779268f

// ---- pure-VALU cross-lane add within each 16-lane row (no LDS pipe) ----
// dpp ctrl must be an integer constant expression -> template parameter.
template <int CTRL>
__device__ __forceinline__ float dpp_add(float x) {
    union { float f; int i; } a, b;
    a.f = x;
    b.i = __builtin_amdgcn_update_dpp(0, a.i, CTRL, 0xF, 0xF, true);
    return x + b.f;
}
// full 16-lane sum, result broadcast to all 16 lanes:
// quad_perm xor1, quad_perm xor2 (quad sums), then rotate-4, rotate-8.
__device__ __forceinline__ float sum16(float t) {
    t = dpp_add<0xB1>(t);   // quad_perm [1,0,3,2]  == xor 1
    t = dpp_add<0x4E>(t);   // quad_perm [2,3,0,1]  == xor 2
    t = dpp_add<0x124>(t);  // row_ror:4
    t = dpp_add<0x128>(t);  // row_ror:8
    return t;
}

__global__ __launch_bounds__(THREADS) void ltfgw_kernel(
    const float* __restrict__ x,      // [N,128]
    const int*   __restrict__ ei,     // edge_index[0], [N*DEG]
    const float* __restrict__ tmpl,   // [T,K,K]
    const float* __restrict__ tf,     // [T,K,128]
    float* __restrict__ out,          // [N,T]
    int N)
{
    constexpr int SLAB = MM * DD + 4;   // +4 floats: node slabs land on disjoint banks
    __shared__ float sFi[NPB * SLAB];
    __shared__ float sNrm[NPB][MM];

    const int tid = threadIdx.x;
    const int b0  = blockIdx.x * NPB;

    // ---- stage Fi: 68 rows of 128 floats, 32 lanes of float4 per row
    {
        const int kq = tid & 31;
        for (int r = tid >> 5; r < NPB * MM; r += (THREADS >> 5)) {
            int p = r / MM, j = r % MM;
            int node = b0 + p;
            if (node < N) {
                int src = (j == 0) ? node : ei[node * DEG + (j - 1)];
                float4 v = *(const float4*)(x + (size_t)src * DD + kq * 4);
                *(float4*)(&sFi[p * SLAB + j * DD + kq * 4]) = v;
            }
        }
    }
    __syncthreads();

    // ---- per-row squared norms
    if (tid < NPB * MM) {
        int p = tid / MM, j = tid % MM;
        const float* row = &sFi[p * SLAB + j * DD];
        float acc = 0.f;
        for (int kidx = 0; kidx < 32; ++kidx) {
            int kq2 = (kidx + tid) & 31;
            float4 v = *(const float4*)(row + kq2 * 4);
            acc += v.x * v.x + v.y * v.y + v.z * v.z + v.w * v.w;
        }
        sNrm[p][j] = acc;
    }
    __syncthreads();

    const int w    = tid >> 6;         // template index
    const int lane = tid & 63;
    const int p    = lane >> 4;        // node sub-slot 0..3
    const int c    = lane & 15;        // template column (active if <10)
    const bool act = (c < KT);
    const int node = b0 + p;
    const int cc   = act ? c : 0;

    // ---- Ct row + ct2q = (Ct^2 @ q)[c]
    float CtRow[KT];
    float ct2q = 0.f;
#pragma unroll
    for (int jj = 0; jj < KT; ++jj) {
        CtRow[jj] = tmpl[(w * KT + cc) * KT + jj];
        ct2q += CtRow[jj] * CtRow[jj];
    }
    ct2q *= (1.f / KT);

    // ---- M[j][c] = (||Fi_j||^2 + ||Ft_c||^2 - 2*dot) / 128
    float dot[MM];
#pragma unroll
    for (int j = 0; j < MM; ++j) dot[j] = 0.f;
    float nft = 0.f;
    const float* ftrow = tf + (size_t)(w * KT + cc) * DD;
    for (int kk = 0; kk < DD; kk += 4) {
        float4 f4 = *(const float4*)(ftrow + kk);
        nft += f4.x * f4.x + f4.y * f4.y + f4.z * f4.z + f4.w * f4.w;
#pragma unroll
        for (int j = 0; j < MM; ++j) {
            float4 a4 = *(const float4*)(&sFi[p * SLAB + j * DD + kk]);
            dot[j] += a4.x * f4.x + a4.y * f4.y + a4.z * f4.z + a4.w * f4.w;
        }
    }
    float Mc[MM];
#pragma unroll
    for (int j = 0; j < MM; ++j)
        Mc[j] = act ? (sNrm[p][j] + nft - 2.f * dot[j]) * (1.f / DD) : 0.f;

    // ---- scaled-domain proximal Sinkhorn (pw folded out of the u-update)
    const float pw = 1.f / MM;
    const float QP = 17.f / 10.f;      // qw / pw
    const int gbase = lane & ~15;

    float Tp[MM], eK[MM], u1[MM];
#pragma unroll
    for (int j = 0; j < MM; ++j) Tp[j] = act ? (1.f / (MM * KT)) : 0.f;

    float obj = 0.f;

#pragma unroll 1
    for (int outer = 0; outer <= 5; ++outer) {
        float colsum = 0.f;
#pragma unroll
        for (int j = 0; j < MM; ++j) colsum += Tp[j];
        float t0 = Tp[0];
        float s  = colsum - t0;

        // (Ci@Tp@Ct^T): row0 -> Ct . s ; rows>=1 -> Ct . Tp[0,:]
        float Cs = 0.f, C0 = 0.f;
#pragma unroll
        for (int jj = 0; jj < KT; ++jj) {
            float sv = __shfl(s,  gbase + jj, 64);
            float tv = __shfl(t0, gbase + jj, 64);
            Cs += CtRow[jj] * sv;
            C0 += CtRow[jj] * tv;
        }

        if (outer == 5) {
#pragma unroll
            for (int j = 0; j < MM; ++j) {
                float gw = ((j == 0) ? (16.f / 17.f) : (1.f / 17.f)) + ct2q
                           - 2.f * ((j == 0) ? Cs : C0);
                obj += Tp[j] * (0.5f * Mc[j] + 0.5f * gw);
            }
            break;
        }

        // mirror step: eK = Tp * exp(-cost/EPS)
#pragma unroll
        for (int j = 0; j < MM; ++j) {
            float gw = ((j == 0) ? (16.f / 17.f) : (1.f / 17.f)) + ct2q
                       - 2.f * ((j == 0) ? Cs : C0);
            float cost = 0.5f * Mc[j] + gw;
            eK[j] = act ? Tp[j] * FEXP2(-TWO_LOG2E * cost) : 0.f;
        }

        // 10 Sinkhorn iterations; u1 = 1/(K v), v = (qw/pw)/(K^T u1)
        float v = 1.f;
#pragma unroll 1
        for (int it = 0; it < 10; ++it) {
            float colacc = 0.f;
#pragma unroll
            for (int j = 0; j < MM; ++j) {
                float t = sum16(eK[j] * v);
                u1[j] = FRCP(t);
                colacc = fmaf(eK[j], u1[j], colacc);
            }
            v = act ? QP * FRCP(colacc) : 0.f;
        }

        float pv = pw * v;
#pragma unroll
        for (int j = 0; j < MM; ++j) Tp[j] = eK[j] * u1[j] * pv;
    }

    // sum over the 16-lane group (inactive lanes contribute exact 0)
    obj = sum16(obj);

    if (act && c == 0 && node < N) out[node * TT + w] = obj;
}

extern "C" void kernel_launch(void* const* d_in, const int* in_sizes, int n_in,
                              void* d_out, int out_size, void* d_ws, size_t ws_size,
                              hipStream_t stream) {
    const float* x    = (const float*)d_in[0];
    const int*   ei   = (const int*)d_in[1];
    const float* tmpl = (const float*)d_in[2];
    const float* tf   = (const float*)d_in[3];
    float* out = (float*)d_out;
    int N = in_sizes[0] / DD;
    int grid = (N + NPB - 1) / NPB;
    hipLaunchKernelGGL(ltfgw_kernel, dim3(grid), dim3(THREADS), 0, stream,
                       x, ei, tmpl, tf, out, N);
}